// Round 14
// baseline (42.455 us; speedup 1.0000x reference)
//
#include <hip/hip_runtime.h>
#include <math.h>

#define NROWS 65536
#define DDIM 512
#define NUM_CLASSES 1000
#define NHB 16
#define RPHB (NROWS / NHB)
#define NSHARD 8

// ws layout (32-bit elems):
//   [0,16000)        int   hist partials [NHB][NUM_CLASSES]
//   [16384,81920)    int   sorted row indices
//   [81920,90112)    float 8 sharded bins
#define HIST_OFF 0
#define SORT_OFF 16384
#define BINS_OFF (16384 + NROWS)
#define WS_NEED ((size_t)(BINS_OFF + NSHARD * 1024) * 4)

__device__ inline float sqdiff4(float4 a, float4 b) {
    float dx = a.x - b.x, dy = a.y - b.y, dz = a.z - b.z, dw = a.w - b.w;
    return fmaf(dx, dx, fmaf(dy, dy, fmaf(dz, dz, dw * dw)));
}

// --- K1: per-block label histogram ---
__global__ __launch_bounds__(1024) void CL_hist(
    const int* __restrict__ labels, int* __restrict__ wsI)
{
    __shared__ int cnt[NUM_CLASSES];
    const int t = threadIdx.x;
    if (t < NUM_CLASSES) cnt[t] = 0;
    __syncthreads();
    const int base = blockIdx.x * RPHB;
#pragma unroll
    for (int i = 0; i < RPHB / 1024; ++i)
        atomicAdd(&cnt[labels[base + i * 1024 + t]], 1);
    __syncthreads();
    if (t < NUM_CLASSES)
        wsI[HIST_OFF + blockIdx.x * NUM_CLASSES + t] = cnt[t];
}

// --- K2: scan + scatter row indices; block 0 zeroes bins ---
__global__ __launch_bounds__(1024) void CL_scatter(
    const int* __restrict__ labels, int* __restrict__ wsI,
    float* __restrict__ wsF)
{
    __shared__ int scanbuf[1024];
    __shared__ int basech[NUM_CLASSES];
    __shared__ int lcnt[NUM_CLASSES];
    const int t = threadIdx.x;

    if (blockIdx.x == 0) {
#pragma unroll
        for (int i = 0; i < NSHARD; ++i)
            wsF[BINS_OFF + i * 1024 + t] = 0.0f;
    }

    int colsum = 0, myoff = 0;
    if (t < NUM_CLASSES) {
        for (int b = 0; b < NHB; ++b) {
            const int v = wsI[HIST_OFF + b * NUM_CLASSES + t];
            colsum += v;
            if (b < (int)blockIdx.x) myoff += v;
        }
    }
    scanbuf[t] = (t < NUM_CLASSES) ? colsum : 0;
    __syncthreads();
    for (int off = 1; off < 1024; off <<= 1) {
        int v = scanbuf[t];
        if (t >= off) v += scanbuf[t - off];
        __syncthreads();
        scanbuf[t] = v;
        __syncthreads();
    }
    if (t < NUM_CLASSES) {
        basech[t] = ((t == 0) ? 0 : scanbuf[t - 1]) + myoff;
        lcnt[t] = 0;
    }
    __syncthreads();

    const int base = blockIdx.x * RPHB;
#pragma unroll
    for (int i = 0; i < RPHB / 1024; ++i) {
        const int r = base + i * 1024 + t;
        const int l = labels[r];
        const int pos = basech[l] + atomicAdd(&lcnt[l], 1);
        wsI[SORT_OFF + pos] = r;
    }
}

// --- K3: 8 sorted rows per wave; uniform-label fast path reuses the center ---
__global__ __launch_bounds__(256) void CL_accum_sorted2(
    const float* __restrict__ x,
    const int* __restrict__ labels,
    const float* __restrict__ centers,
    const int* __restrict__ wsI,
    float* __restrict__ wsF)
{
    const int lane = threadIdx.x & 63;
    const int wid  = (blockIdx.x << 2) + (threadIdx.x >> 6);   // 0..8191
    const int base = wid << 3;                                  // 8 sorted rows

    int sr = 0, sl = 0;
    if (lane < 8) {
        sr = wsI[SORT_OFF + base + lane];
        sl = labels[sr];
    }
    const int l0 = __shfl(sl, 0, 64);
    const unsigned long long bal =
        __ballot((lane < 8) ? (sl == l0) : true);
    const bool uni = (bal == ~0ull);

    float* __restrict__ bins =
        wsF + BINS_OFF + ((wid & (NSHARD - 1)) << 10);

    if (uni) {
        // ---- fast path (~88% of waves): one center, 8 rows, one atomic ----
        const float4* __restrict__ cr =
            reinterpret_cast<const float4*>(centers + (size_t)l0 * DDIM);
        const float4 c0 = cr[lane], c1 = cr[lane + 64];

        const int r0 = __shfl(sr, 0, 64), r1 = __shfl(sr, 1, 64);
        const int r2 = __shfl(sr, 2, 64), r3 = __shfl(sr, 3, 64);
        const int r4 = __shfl(sr, 4, 64), r5 = __shfl(sr, 5, 64);
        const int r6 = __shfl(sr, 6, 64), r7 = __shfl(sr, 7, 64);

        const float4* p0 = (const float4*)(x + (size_t)r0 * DDIM);
        const float4* p1 = (const float4*)(x + (size_t)r1 * DDIM);
        const float4* p2 = (const float4*)(x + (size_t)r2 * DDIM);
        const float4* p3 = (const float4*)(x + (size_t)r3 * DDIM);
        const float4* p4 = (const float4*)(x + (size_t)r4 * DDIM);
        const float4* p5 = (const float4*)(x + (size_t)r5 * DDIM);
        const float4* p6 = (const float4*)(x + (size_t)r6 * DDIM);
        const float4* p7 = (const float4*)(x + (size_t)r7 * DDIM);

        float racc =
            sqdiff4(p0[lane], c0) + sqdiff4(p0[lane + 64], c1) +
            sqdiff4(p1[lane], c0) + sqdiff4(p1[lane + 64], c1) +
            sqdiff4(p2[lane], c0) + sqdiff4(p2[lane + 64], c1) +
            sqdiff4(p3[lane], c0) + sqdiff4(p3[lane + 64], c1) +
            sqdiff4(p4[lane], c0) + sqdiff4(p4[lane + 64], c1) +
            sqdiff4(p5[lane], c0) + sqdiff4(p5[lane + 64], c1) +
            sqdiff4(p6[lane], c0) + sqdiff4(p6[lane + 64], c1) +
            sqdiff4(p7[lane], c0) + sqdiff4(p7[lane + 64], c1);

#pragma unroll
        for (int off = 32; off > 0; off >>= 1)
            racc += __shfl_xor(racc, off, 64);
        if (lane == 0) atomicAdd(&bins[l0], racc);
    } else {
        // ---- boundary waves (~12%): per-row serial fallback ----
#pragma unroll 1
        for (int k = 0; k < 8; ++k) {
            const int r = __shfl(sr, k, 64);
            const int l = __shfl(sl, k, 64);
            const float4* __restrict__ cr =
                reinterpret_cast<const float4*>(centers + (size_t)l * DDIM);
            const float4* __restrict__ xr =
                reinterpret_cast<const float4*>(x + (size_t)r * DDIM);
            float a = sqdiff4(xr[lane], cr[lane]) +
                      sqdiff4(xr[lane + 64], cr[lane + 64]);
#pragma unroll
            for (int off = 32; off > 0; off >>= 1)
                a += __shfl_xor(a, off, 64);
            if (lane == 0) atomicAdd(&bins[l], a);
        }
    }
}

// --- K4: sum shards, sqrt, reduce, scale ---
__global__ __launch_bounds__(256) void CL_final8(
    const float* __restrict__ bins, float* __restrict__ out)
{
    const int t = threadIdx.x, lane = t & 63;
    float s = 0.0f;
    if (t < NUM_CLASSES / 4) {
        float4 v = reinterpret_cast<const float4*>(bins)[t];
#pragma unroll
        for (int sh = 1; sh < NSHARD; ++sh) {
            float4 u = reinterpret_cast<const float4*>(bins + (sh << 10))[t];
            v.x += u.x; v.y += u.y; v.z += u.z; v.w += u.w;
        }
        s = sqrtf(v.x) + sqrtf(v.y) + sqrtf(v.z) + sqrtf(v.w);
    }
#pragma unroll
    for (int off = 32; off > 0; off >>= 1)
        s += __shfl_xor(s, off, 64);
    __shared__ float partial[4];
    if (lane == 0) partial[t >> 6] = s;
    __syncthreads();
    if (t == 0)
        out[0] = (partial[0] + partial[1] + partial[2] + partial[3])
                 / (float)NUM_CLASSES;
}

// ---------------- fallback (proven R8) if ws too small ----------------
__global__ __launch_bounds__(256) void CL_zero8(float* __restrict__ ws) {
    const int n = NSHARD * 1024;
    for (int i = threadIdx.x + blockIdx.x * 256; i < n; i += 256 * 8) ws[i] = 0.0f;
}
__global__ __launch_bounds__(256) void CL_accum8(
    const float* __restrict__ x, const int* __restrict__ labels,
    const float* __restrict__ centers, float* __restrict__ ws)
{
    const int wave = threadIdx.x >> 6, lane = threadIdx.x & 63;
    const int row = (blockIdx.x << 2) + wave;
    const int lbl = labels[row];
    const float4* xr = (const float4*)(x + (size_t)row * DDIM);
    const float4* cr = (const float4*)(centers + (size_t)lbl * DDIM);
    float acc = sqdiff4(xr[lane], cr[lane]) + sqdiff4(xr[lane + 64], cr[lane + 64]);
#pragma unroll
    for (int off = 32; off > 0; off >>= 1) acc += __shfl_xor(acc, off, 64);
    if (lane == 0)
        atomicAdd(&ws[((blockIdx.x & (NSHARD - 1)) << 10) + lbl], acc);
}

extern "C" void kernel_launch(void* const* d_in, const int* in_sizes, int n_in,
                              void* d_out, int out_size, void* d_ws, size_t ws_size,
                              hipStream_t stream) {
    const float* x       = (const float*)d_in[0];
    const int*   labels  = (const int*)d_in[1];
    const float* centers = (const float*)d_in[2];
    float* out = (float*)d_out;
    float* wsF = (float*)d_ws;
    int*   wsI = (int*)d_ws;

    if (ws_size >= WS_NEED) {
        CL_hist<<<NHB, 1024, 0, stream>>>(labels, wsI);
        CL_scatter<<<NHB, 1024, 0, stream>>>(labels, wsI, wsF);
        CL_accum_sorted2<<<NROWS / 32, 256, 0, stream>>>(x, labels, centers, wsI, wsF);
        CL_final8<<<1, 256, 0, stream>>>(wsF + BINS_OFF, out);
    } else {
        CL_zero8<<<8, 256, 0, stream>>>(wsF);
        CL_accum8<<<NROWS / 4, 256, 0, stream>>>(x, labels, centers, wsF);
        CL_final8<<<1, 256, 0, stream>>>(wsF, out);
    }
}

// Round 16
// 39.890 us; speedup vs baseline: 1.0643x; 1.0643x over previous
//
#include <hip/hip_runtime.h>
#include <math.h>

#define NROWS 65536
#define DDIM 512
#define NUM_CLASSES 1000
#define NSHARD 8

typedef float floatx4 __attribute__((ext_vector_type(4)));

// --- kernel 1: zero the 8 sharded bin arrays ---
__global__ __launch_bounds__(256) void CL_zero8(float* __restrict__ ws) {
    const int n = NSHARD * 1024;
    for (int i = threadIdx.x + blockIdx.x * 256; i < n; i += 256 * 8)
        ws[i] = 0.0f;
}

__device__ inline float sqdiff4v(floatx4 a, floatx4 b) {
    floatx4 d = a - b;
    return fmaf(d.x, d.x, fmaf(d.y, d.y, fmaf(d.z, d.z, d.w * d.w)));
}

// --- kernel 2: R8 body (one wave per row, 8-way sharded atomics), with
// NON-TEMPORAL x loads (ext_vector_type for the builtin). x has zero reuse
// -> nt bypasses L1 allocation; centers (the only reused data) keep normal
// caching. Tests whether the ~16 B/cyc/CU ceiling (R7: 27.9 us/pass) is an
// L1-allocation limit (nt helps) or the TCP return path (flat). ---
__global__ __launch_bounds__(256) void CL_accum8(
    const float* __restrict__ x,
    const int* __restrict__ labels,
    const float* __restrict__ centers,
    float* __restrict__ ws)
{
    const int wave = threadIdx.x >> 6;
    const int lane = threadIdx.x & 63;
    const int row  = (blockIdx.x << 2) + wave;
    const int lbl  = labels[row];

    const floatx4* __restrict__ xr =
        reinterpret_cast<const floatx4*>(x + (size_t)row * DDIM);
    const floatx4* __restrict__ cr =
        reinterpret_cast<const floatx4*>(centers + (size_t)lbl * DDIM);

    // streaming (non-temporal) x reads: no L1 allocation
    const floatx4 xv0 = __builtin_nontemporal_load(&xr[lane]);
    const floatx4 xv1 = __builtin_nontemporal_load(&xr[lane + 64]);
    // centers: normal cached reads (2 MB working set, real reuse)
    const floatx4 cv0 = cr[lane];
    const floatx4 cv1 = cr[lane + 64];

    float acc = sqdiff4v(xv0, cv0) + sqdiff4v(xv1, cv1);

#pragma unroll
    for (int off = 32; off > 0; off >>= 1)
        acc += __shfl_xor(acc, off, 64);

    if (lane == 0)
        atomicAdd(&ws[((blockIdx.x & (NSHARD - 1)) << 10) + lbl], acc);
}

// --- kernel 3: sum 8 shards, sqrt, reduce, scale ---
__global__ __launch_bounds__(256) void CL_final8(
    const float* __restrict__ ws, float* __restrict__ out)
{
    const int t = threadIdx.x, lane = t & 63;
    float s = 0.0f;
    if (t < NUM_CLASSES / 4) {               // 250 threads, 1000 = 250 float4
        float4 v = reinterpret_cast<const float4*>(ws)[t];
#pragma unroll
        for (int sh = 1; sh < NSHARD; ++sh) {
            float4 u = reinterpret_cast<const float4*>(ws + (sh << 10))[t];
            v.x += u.x; v.y += u.y; v.z += u.z; v.w += u.w;
        }
        s = sqrtf(v.x) + sqrtf(v.y) + sqrtf(v.z) + sqrtf(v.w);
    }
#pragma unroll
    for (int off = 32; off > 0; off >>= 1)
        s += __shfl_xor(s, off, 64);

    __shared__ float partial[4];
    if (lane == 0) partial[t >> 6] = s;
    __syncthreads();
    if (t == 0)
        out[0] = (partial[0] + partial[1] + partial[2] + partial[3])
                 / (float)NUM_CLASSES;
}

extern "C" void kernel_launch(void* const* d_in, const int* in_sizes, int n_in,
                              void* d_out, int out_size, void* d_ws, size_t ws_size,
                              hipStream_t stream) {
    const float* x       = (const float*)d_in[0];
    const int*   labels  = (const int*)d_in[1];
    const float* centers = (const float*)d_in[2];
    float* out = (float*)d_out;
    float* ws  = (float*)d_ws;

    CL_zero8<<<8, 256, 0, stream>>>(ws);
    CL_accum8<<<NROWS / 4, 256, 0, stream>>>(x, labels, centers, ws);
    CL_final8<<<1, 256, 0, stream>>>(ws, out);
}

// Round 17
// 32.660 us; speedup vs baseline: 1.2999x; 1.2214x over previous
//
#include <hip/hip_runtime.h>
#include <math.h>

#define NROWS 65536
#define DDIM 512
#define NUM_CLASSES 1000
#define CG 16                      // column groups (32 floats = 128 B each)
#define RC 16                      // row chunks
#define RPB (NROWS / RC)           // 4096 rows per block
#define CSTRIDE 36                 // LDS center-slice stride: 16B-aligned, bank-rotating

// ws layout: [0, 256000) float partials[256][1000]; [256000, 257000) sqrt vals
#define PART_OFF 0
#define SQRT_OFF (256 * NUM_CLASSES)
#define WS_NEED ((size_t)(SQRT_OFF + NUM_CLASSES) * 4)

__device__ inline float sqdiff4(float4 a, float4 b) {
    float dx = a.x - b.x, dy = a.y - b.y, dz = a.z - b.z, dw = a.w - b.w;
    return fmaf(dx, dx, fmaf(dy, dy, fmaf(dz, dz, dw * dw)));
}

// --- K1: column-sliced accumulate, centers slice resident in LDS ---
__global__ __launch_bounds__(1024) void CL_slice(
    const float* __restrict__ x,
    const int* __restrict__ labels,
    const float* __restrict__ centers,
    float* __restrict__ partials)
{
    __shared__ float cs[NUM_CLASSES * CSTRIDE];   // 144,000 B
    __shared__ float bins[NUM_CLASSES];           //   4,000 B
    const int t  = threadIdx.x;
    const int cg = blockIdx.x & (CG - 1);
    const int rc = blockIdx.x >> 4;
    const int cq = t & 7;                         // col quad within slice
    const int tr = t >> 3;                        // 0..127

    // stage centers slice [1000][32] -> cs (ds_write_b128, 16B-aligned)
    for (int k = tr; k < NUM_CLASSES; k += 128) {
        const float4 c = *reinterpret_cast<const float4*>(
            centers + (size_t)k * DDIM + cg * 32 + cq * 4);
        *reinterpret_cast<float4*>(cs + k * CSTRIDE + cq * 4) = c;
    }
    if (t < NUM_CLASSES) bins[t] = 0.0f;
    __syncthreads();

    const int rowbase = rc * RPB;
    const float* __restrict__ xcg = x + cg * 32 + cq * 4;

#pragma unroll 4
    for (int i = 0; i < RPB; i += 256) {
        const int rA = rowbase + i + tr;
        const int rB = rA + 128;
        const float4 xa = *reinterpret_cast<const float4*>(xcg + (size_t)rA * DDIM);
        const float4 xb = *reinterpret_cast<const float4*>(xcg + (size_t)rB * DDIM);
        const int la = labels[rA];
        const int lb = labels[rB];
        const float4 ca = *reinterpret_cast<const float4*>(cs + la * CSTRIDE + cq * 4);
        const float4 cb = *reinterpret_cast<const float4*>(cs + lb * CSTRIDE + cq * 4);

        float sa = sqdiff4(xa, ca);
        float sb = sqdiff4(xb, cb);
        // reduce across the 8 lanes of this row (xor 1,2,4 stays in-group)
        sa += __shfl_xor(sa, 1, 64);  sb += __shfl_xor(sb, 1, 64);
        sa += __shfl_xor(sa, 2, 64);  sb += __shfl_xor(sb, 2, 64);
        sa += __shfl_xor(sa, 4, 64);  sb += __shfl_xor(sb, 4, 64);
        if (cq == 0) {
            atomicAdd(&bins[la], sa);     // LDS atomic, block-local
            atomicAdd(&bins[lb], sb);
        }
    }

    __syncthreads();
    if (t < NUM_CLASSES)
        partials[(size_t)blockIdx.x * NUM_CLASSES + t] = bins[t];
}

// --- K2: 250 blocks x 4 classes: sum 256 partials, sqrt, store ---
__global__ __launch_bounds__(256) void CL_reduce(
    const float* __restrict__ partials, float* __restrict__ sqv)
{
    const int t = threadIdx.x, lane = t & 63, w = t >> 6;
    __shared__ float acc[4][4];
#pragma unroll
    for (int j = 0; j < 4; ++j) {
        const int k = blockIdx.x * 4 + j;
        float v = partials[(size_t)t * NUM_CLASSES + k];
#pragma unroll
        for (int off = 32; off > 0; off >>= 1)
            v += __shfl_xor(v, off, 64);
        if (lane == 0) acc[w][j] = v;
    }
    __syncthreads();
    if (t < 4) {
        const float s = acc[0][t] + acc[1][t] + acc[2][t] + acc[3][t];
        sqv[blockIdx.x * 4 + t] = sqrtf(s);
    }
}

// --- K3: sum the 1000 sqrt values, scale ---
__global__ __launch_bounds__(256) void CL_sum(
    const float* __restrict__ sqv, float* __restrict__ out)
{
    const int t = threadIdx.x, lane = t & 63;
    float s = 0.0f;
    if (t < NUM_CLASSES / 4) {
        const float4 v = reinterpret_cast<const float4*>(sqv)[t];
        s = (v.x + v.y) + (v.z + v.w);
    }
#pragma unroll
    for (int off = 32; off > 0; off >>= 1)
        s += __shfl_xor(s, off, 64);
    __shared__ float partial[4];
    if (lane == 0) partial[t >> 6] = s;
    __syncthreads();
    if (t == 0)
        out[0] = (partial[0] + partial[1] + partial[2] + partial[3])
                 / (float)NUM_CLASSES;
}

// ---------------- fallback (proven R8, 36.9 µs) if ws too small ----------------
#define NSHARD 8
__global__ __launch_bounds__(256) void CL_zero8(float* __restrict__ ws) {
    const int n = NSHARD * 1024;
    for (int i = threadIdx.x + blockIdx.x * 256; i < n; i += 256 * 8) ws[i] = 0.0f;
}
__global__ __launch_bounds__(256) void CL_accum8(
    const float* __restrict__ x, const int* __restrict__ labels,
    const float* __restrict__ centers, float* __restrict__ ws)
{
    const int wave = threadIdx.x >> 6, lane = threadIdx.x & 63;
    const int row = (blockIdx.x << 2) + wave;
    const int lbl = labels[row];
    const float4* xr = (const float4*)(x + (size_t)row * DDIM);
    const float4* cr = (const float4*)(centers + (size_t)lbl * DDIM);
    float acc = sqdiff4(xr[lane], cr[lane]) + sqdiff4(xr[lane + 64], cr[lane + 64]);
#pragma unroll
    for (int off = 32; off > 0; off >>= 1) acc += __shfl_xor(acc, off, 64);
    if (lane == 0)
        atomicAdd(&ws[((blockIdx.x & (NSHARD - 1)) << 10) + lbl], acc);
}
__global__ __launch_bounds__(256) void CL_final8(
    const float* __restrict__ ws, float* __restrict__ out)
{
    const int t = threadIdx.x, lane = t & 63;
    float s = 0.0f;
    if (t < NUM_CLASSES / 4) {
        float4 v = reinterpret_cast<const float4*>(ws)[t];
#pragma unroll
        for (int sh = 1; sh < NSHARD; ++sh) {
            float4 u = reinterpret_cast<const float4*>(ws + (sh << 10))[t];
            v.x += u.x; v.y += u.y; v.z += u.z; v.w += u.w;
        }
        s = sqrtf(v.x) + sqrtf(v.y) + sqrtf(v.z) + sqrtf(v.w);
    }
#pragma unroll
    for (int off = 32; off > 0; off >>= 1) s += __shfl_xor(s, off, 64);
    __shared__ float partial[4];
    if (lane == 0) partial[t >> 6] = s;
    __syncthreads();
    if (t == 0)
        out[0] = (partial[0] + partial[1] + partial[2] + partial[3]) / (float)NUM_CLASSES;
}

extern "C" void kernel_launch(void* const* d_in, const int* in_sizes, int n_in,
                              void* d_out, int out_size, void* d_ws, size_t ws_size,
                              hipStream_t stream) {
    const float* x       = (const float*)d_in[0];
    const int*   labels  = (const int*)d_in[1];
    const float* centers = (const float*)d_in[2];
    float* out = (float*)d_out;
    float* ws  = (float*)d_ws;

    if (ws_size >= WS_NEED) {
        CL_slice<<<CG * RC, 1024, 0, stream>>>(x, labels, centers, ws + PART_OFF);
        CL_reduce<<<NUM_CLASSES / 4, 256, 0, stream>>>(ws + PART_OFF, ws + SQRT_OFF);
        CL_sum<<<1, 256, 0, stream>>>(ws + SQRT_OFF, out);
    } else {
        CL_zero8<<<8, 256, 0, stream>>>(ws);
        CL_accum8<<<NROWS / 4, 256, 0, stream>>>(x, labels, centers, ws);
        CL_final8<<<1, 256, 0, stream>>>(ws, out);
    }
}

// Round 18
// 32.268 us; speedup vs baseline: 1.3157x; 1.0121x over previous
//
#include <hip/hip_runtime.h>
#include <math.h>

#define NROWS 65536
#define DDIM 512
#define NUM_CLASSES 1000
#define CG 16                      // column groups (32 floats = 128 B each)
#define RC 16                      // row chunks
#define RPB (NROWS / RC)           // 4096 rows per block
#define CSTRIDE 36                 // LDS center-slice stride: 16B-aligned, bank-rotating

// ws layout: [0, 256000) float partials[1000][256]  (class-major!)
//            [256000, 257000) sqrt vals
#define PART_OFF 0
#define SQRT_OFF (256 * NUM_CLASSES)
#define WS_NEED ((size_t)(SQRT_OFF + NUM_CLASSES) * 4)

__device__ inline float sqdiff4(float4 a, float4 b) {
    float dx = a.x - b.x, dy = a.y - b.y, dz = a.z - b.z, dw = a.w - b.w;
    return fmaf(dx, dx, fmaf(dy, dy, fmaf(dz, dz, dw * dw)));
}

// --- K1: column-sliced accumulate, centers slice resident in LDS ---
__global__ __launch_bounds__(1024) void CL_slice(
    const float* __restrict__ x,
    const int* __restrict__ labels,
    const float* __restrict__ centers,
    float* __restrict__ partials)
{
    __shared__ float cs[NUM_CLASSES * CSTRIDE];   // 144,000 B
    __shared__ float bins[NUM_CLASSES];           //   4,000 B
    const int t  = threadIdx.x;
    const int cg = blockIdx.x & (CG - 1);
    const int rc = blockIdx.x >> 4;
    const int cq = t & 7;                         // col quad within slice
    const int tr = t >> 3;                        // 0..127

    // stage centers slice [1000][32] -> cs (ds_write_b128, 16B-aligned)
    for (int k = tr; k < NUM_CLASSES; k += 128) {
        const float4 c = *reinterpret_cast<const float4*>(
            centers + (size_t)k * DDIM + cg * 32 + cq * 4);
        *reinterpret_cast<float4*>(cs + k * CSTRIDE + cq * 4) = c;
    }
    if (t < NUM_CLASSES) bins[t] = 0.0f;
    __syncthreads();

    const int rowbase = rc * RPB;
    const float* __restrict__ xcg = x + cg * 32 + cq * 4;

#pragma unroll 4
    for (int i = 0; i < RPB; i += 256) {
        const int rA = rowbase + i + tr;
        const int rB = rA + 128;
        const float4 xa = *reinterpret_cast<const float4*>(xcg + (size_t)rA * DDIM);
        const float4 xb = *reinterpret_cast<const float4*>(xcg + (size_t)rB * DDIM);
        const int la = labels[rA];
        const int lb = labels[rB];
        const float4 ca = *reinterpret_cast<const float4*>(cs + la * CSTRIDE + cq * 4);
        const float4 cb = *reinterpret_cast<const float4*>(cs + lb * CSTRIDE + cq * 4);

        float sa = sqdiff4(xa, ca);
        float sb = sqdiff4(xb, cb);
        // reduce across the 8 lanes of this row (xor 1,2,4 stays in-group)
        sa += __shfl_xor(sa, 1, 64);  sb += __shfl_xor(sb, 1, 64);
        sa += __shfl_xor(sa, 2, 64);  sb += __shfl_xor(sb, 2, 64);
        sa += __shfl_xor(sa, 4, 64);  sb += __shfl_xor(sb, 4, 64);
        if (cq == 0) {
            atomicAdd(&bins[la], sa);     // LDS atomic, block-local
            atomicAdd(&bins[lb], sb);
        }
    }

    __syncthreads();
    // class-major store: partials[class][block] -> K2 reads contiguous runs
    if (t < NUM_CLASSES)
        partials[(size_t)t * 256 + blockIdx.x] = bins[t];
}

// --- K2: one wave per class; 256 contiguous partials -> coalesced float4 ---
__global__ __launch_bounds__(256) void CL_reduce(
    const float* __restrict__ partials, float* __restrict__ sqv)
{
    const int t = threadIdx.x, lane = t & 63;
    const int k = blockIdx.x * 4 + (t >> 6);      // this wave's class
    const float4 v =
        reinterpret_cast<const float4*>(partials + (size_t)k * 256)[lane];
    float s = (v.x + v.y) + (v.z + v.w);
#pragma unroll
    for (int off = 32; off > 0; off >>= 1)
        s += __shfl_xor(s, off, 64);
    if (lane == 0) sqv[k] = sqrtf(s);
}

// --- K3: sum the 1000 sqrt values, scale ---
__global__ __launch_bounds__(256) void CL_sum(
    const float* __restrict__ sqv, float* __restrict__ out)
{
    const int t = threadIdx.x, lane = t & 63;
    float s = 0.0f;
    if (t < NUM_CLASSES / 4) {
        const float4 v = reinterpret_cast<const float4*>(sqv)[t];
        s = (v.x + v.y) + (v.z + v.w);
    }
#pragma unroll
    for (int off = 32; off > 0; off >>= 1)
        s += __shfl_xor(s, off, 64);
    __shared__ float partial[4];
    if (lane == 0) partial[t >> 6] = s;
    __syncthreads();
    if (t == 0)
        out[0] = (partial[0] + partial[1] + partial[2] + partial[3])
                 / (float)NUM_CLASSES;
}

// ---------------- fallback (proven R8, 36.9 µs) if ws too small ----------------
#define NSHARD 8
__global__ __launch_bounds__(256) void CL_zero8(float* __restrict__ ws) {
    const int n = NSHARD * 1024;
    for (int i = threadIdx.x + blockIdx.x * 256; i < n; i += 256 * 8) ws[i] = 0.0f;
}
__global__ __launch_bounds__(256) void CL_accum8(
    const float* __restrict__ x, const int* __restrict__ labels,
    const float* __restrict__ centers, float* __restrict__ ws)
{
    const int wave = threadIdx.x >> 6, lane = threadIdx.x & 63;
    const int row = (blockIdx.x << 2) + wave;
    const int lbl = labels[row];
    const float4* xr = (const float4*)(x + (size_t)row * DDIM);
    const float4* cr = (const float4*)(centers + (size_t)lbl * DDIM);
    float acc = sqdiff4(xr[lane], cr[lane]) + sqdiff4(xr[lane + 64], cr[lane + 64]);
#pragma unroll
    for (int off = 32; off > 0; off >>= 1) acc += __shfl_xor(acc, off, 64);
    if (lane == 0)
        atomicAdd(&ws[((blockIdx.x & (NSHARD - 1)) << 10) + lbl], acc);
}
__global__ __launch_bounds__(256) void CL_final8(
    const float* __restrict__ ws, float* __restrict__ out)
{
    const int t = threadIdx.x, lane = t & 63;
    float s = 0.0f;
    if (t < NUM_CLASSES / 4) {
        float4 v = reinterpret_cast<const float4*>(ws)[t];
#pragma unroll
        for (int sh = 1; sh < NSHARD; ++sh) {
            float4 u = reinterpret_cast<const float4*>(ws + (sh << 10))[t];
            v.x += u.x; v.y += u.y; v.z += u.z; v.w += u.w;
        }
        s = sqrtf(v.x) + sqrtf(v.y) + sqrtf(v.z) + sqrtf(v.w);
    }
#pragma unroll
    for (int off = 32; off > 0; off >>= 1) s += __shfl_xor(s, off, 64);
    __shared__ float partial[4];
    if (lane == 0) partial[t >> 6] = s;
    __syncthreads();
    if (t == 0)
        out[0] = (partial[0] + partial[1] + partial[2] + partial[3]) / (float)NUM_CLASSES;
}

extern "C" void kernel_launch(void* const* d_in, const int* in_sizes, int n_in,
                              void* d_out, int out_size, void* d_ws, size_t ws_size,
                              hipStream_t stream) {
    const float* x       = (const float*)d_in[0];
    const int*   labels  = (const int*)d_in[1];
    const float* centers = (const float*)d_in[2];
    float* out = (float*)d_out;
    float* ws  = (float*)d_ws;

    if (ws_size >= WS_NEED) {
        CL_slice<<<CG * RC, 1024, 0, stream>>>(x, labels, centers, ws + PART_OFF);
        CL_reduce<<<NUM_CLASSES / 4, 256, 0, stream>>>(ws + PART_OFF, ws + SQRT_OFF);
        CL_sum<<<1, 256, 0, stream>>>(ws + SQRT_OFF, out);
    } else {
        CL_zero8<<<8, 256, 0, stream>>>(ws);
        CL_accum8<<<NROWS / 4, 256, 0, stream>>>(x, labels, centers, ws);
        CL_final8<<<1, 256, 0, stream>>>(ws, out);
    }
}